// Round 6
// baseline (3407.831 us; speedup 1.0000x reference)
//
#include <hip/hip_runtime.h>
#include <cstdint>
#include <cstddef>

typedef unsigned int u32;
typedef unsigned long long u64;

#define NBATCH 8192
#define SEQLEN 64
#define ZDIM   256
#define HDIM   64
#define NNEUR  128
#define EMID   160
#define DMID   96
#define TILE   32

__device__ __forceinline__ u32 rotl32(u32 v, int s){ return (v << s) | (v >> (32 - s)); }

// Threefry2x32, 20 rounds — exact JAX schedule.
__device__ __forceinline__ void tf2x32(u32 k0, u32 k1, u32 x0, u32 x1, u32& y0, u32& y1){
  u32 ks2 = k0 ^ k1 ^ 0x1BD11BDAu;
  x0 += k0; x1 += k1;
#define TF_R(r) { x0 += x1; x1 = rotl32(x1, (r)); x1 ^= x0; }
  TF_R(13) TF_R(15) TF_R(26) TF_R(6)
  x0 += k1;  x1 += ks2 + 1u;
  TF_R(17) TF_R(29) TF_R(16) TF_R(24)
  x0 += ks2; x1 += k0 + 2u;
  TF_R(13) TF_R(15) TF_R(26) TF_R(6)
  x0 += k0;  x1 += k1 + 3u;
  TF_R(17) TF_R(29) TF_R(16) TF_R(24)
  x0 += k1;  x1 += ks2 + 4u;
  TF_R(13) TF_R(15) TF_R(26) TF_R(6)
  x0 += ks2; x1 += k0 + 5u;
#undef TF_R
  y0 = x0; y1 = x1;
}

__device__ __forceinline__ float sigmf(float x){ return 1.0f / (1.0f + expf(-x)); }

__device__ __forceinline__ float dot4acc(float4 w, float4 v, float a){
  a = fmaf(w.x, v.x, a); a = fmaf(w.y, v.y, a);
  a = fmaf(w.z, v.z, a); a = fmaf(w.w, v.w, a);
  return a;
}

__global__ void __launch_bounds__(256, 1)
bar_decoder_kernel(const float* __restrict__ z,
                   const float* __restrict__ W_enc1, const float* __restrict__ b_enc1,
                   const float* __restrict__ W_enc2, const float* __restrict__ b_enc2,
                   const float* __restrict__ W_ih0,  const float* __restrict__ W_hh0,
                   const float* __restrict__ b_ih0,  const float* __restrict__ b_hh0,
                   const float* __restrict__ W_ih1,  const float* __restrict__ W_hh1,
                   const float* __restrict__ b_ih1,  const float* __restrict__ b_hh1,
                   const float* __restrict__ W_dec1, const float* __restrict__ b_dec1,
                   const float* __restrict__ W_dec2, const float* __restrict__ b_dec2,
                   float* __restrict__ out)   // f32! weights [0,2^26), samples [2^26, 2^26+2^19)
{
  __shared__ __align__(16) char buf[53760];
  float* zb    = (float*)buf;
  float* mid   = (float*)(buf + 32768);
  float* encv  = (float*)buf;
  float* xg0s  = (float*)(buf + 8704);
  float* h0    = (float*)buf;
  float* h1    = (float*)(buf + 8704);
  float* d1    = (float*)(buf + 17408);
  float* lg    = (float*)(buf + 30208);
  float* bias1 = (float*)(buf + 46592);
  u32*   keyw  = (u32*)  (buf + 47616);

  const int t = threadIdx.x;
  const int tile0 = blockIdx.x * TILE;

  // ---------------- encoder (once) ----------------
  {
    const float4* zsrc = (const float4*)(z + (size_t)tile0 * ZDIM);
    float4* zdst = (float4*)zb;
    #pragma unroll
    for (int i = 0; i < 8; ++i) zdst[t + 256 * i] = zsrc[t + 256 * i];
  }
  __syncthreads();

  if (t < EMID) {                      // mid = relu(zb @ W1^T + b1)
    float acc[TILE];
    float bb = b_enc1[t];
    #pragma unroll
    for (int b = 0; b < TILE; ++b) acc[b] = bb;
    const float4* wr = (const float4*)(W_enc1 + (size_t)t * ZDIM);
    #pragma unroll 2
    for (int k4 = 0; k4 < 64; ++k4){
      float4 w = wr[k4];
      #pragma unroll
      for (int b = 0; b < TILE; ++b){
        float4 v = ((const float4*)zb)[b * 64 + k4];
        acc[b] = dot4acc(w, v, acc[b]);
      }
    }
    #pragma unroll
    for (int b = 0; b < TILE; ++b) mid[b * 164 + t] = fmaxf(acc[b], 0.0f);
  }
  __syncthreads();

  if (t < HDIM) {                      // enc = mid @ W2^T + b2
    float acc[TILE];
    float bb = b_enc2[t];
    #pragma unroll
    for (int b = 0; b < TILE; ++b) acc[b] = bb;
    const float4* wr = (const float4*)(W_enc2 + (size_t)t * EMID);
    #pragma unroll 2
    for (int k4 = 0; k4 < 40; ++k4){
      float4 w = wr[k4];
      #pragma unroll
      for (int b = 0; b < TILE; ++b){
        float4 v = ((const float4*)mid)[b * 41 + k4];
        acc[b] = dot4acc(w, v, acc[b]);
      }
    }
    #pragma unroll
    for (int b = 0; b < TILE; ++b) encv[b * 68 + t] = acc[b];
  }
  __syncthreads();

  {                                    // xg0 = enc @ Wih0^T + bih0 + bhh0
    float acc[TILE];
    float bb = b_ih0[t] + b_hh0[t];
    #pragma unroll
    for (int b = 0; b < TILE; ++b) acc[b] = bb;
    const float4* wr = (const float4*)(W_ih0 + (size_t)t * HDIM);
    #pragma unroll 4
    for (int k4 = 0; k4 < 16; ++k4){
      float4 w = wr[k4];
      #pragma unroll
      for (int b = 0; b < TILE; ++b){
        float4 v = ((const float4*)encv)[b * 17 + k4];
        acc[b] = dot4acc(w, v, acc[b]);
      }
    }
    #pragma unroll
    for (int b = 0; b < TILE; ++b) xg0s[b * 256 + t] = acc[b];
  }
  __syncthreads();

  // thread roles for LSTM phases
  const int w_id = t >> 6;
  const int l    = t & 63;
  const int j    = w_id * 16 + (l & 15);  // hidden unit 0..63
  const int bg   = l >> 4;                // batch group 0..3 (8 each)

  float xg0r[4][8];
  #pragma unroll
  for (int g = 0; g < 4; ++g)
    #pragma unroll
    for (int bi = 0; bi < 8; ++bi)
      xg0r[g][bi] = xg0s[(bg * 8 + bi) * 256 + g * 64 + j];
  __syncthreads();

  // init state, fused biases, per-step keys (foldlike/partitionable split of key 42)
  for (int i = t; i < 32 * 68; i += 256){ h0[i] = 0.0f; h1[i] = 0.0f; }
  bias1[t] = b_ih1[t] + b_hh1[t];
  if (t < SEQLEN) {
    u32 a0, a1;
    tf2x32(0u, 42u, 0u, (u32)t, a0, a1);
    keyw[2 * t] = a0; keyw[2 * t + 1] = a1;
  }
  float c0r[8], c1r[8];
  #pragma unroll
  for (int bi = 0; bi < 8; ++bi){ c0r[bi] = 0.0f; c1r[bi] = 0.0f; }
  __syncthreads();

  const float4* Whh0_4 = (const float4*)W_hh0;
  const float4* Wih1_4 = (const float4*)W_ih1;
  const float4* Whh1_4 = (const float4*)W_hh1;

  for (int s = 0; s < SEQLEN; ++s){
    // ---------- layer 0 ----------
    float acc[4][8];
    #pragma unroll
    for (int g = 0; g < 4; ++g)
      #pragma unroll
      for (int bi = 0; bi < 8; ++bi) acc[g][bi] = xg0r[g][bi];

    #pragma unroll 4
    for (int k4 = 0; k4 < 16; ++k4){
      float4 wv[4];
      #pragma unroll
      for (int g = 0; g < 4; ++g) wv[g] = Whh0_4[(g * 64 + j) * 16 + k4];
      #pragma unroll
      for (int bi = 0; bi < 8; ++bi){
        float4 hv = ((const float4*)h0)[(bg * 8 + bi) * 17 + k4];
        #pragma unroll
        for (int g = 0; g < 4; ++g) acc[g][bi] = dot4acc(wv[g], hv, acc[g][bi]);
      }
    }
    float h0n[8];
    #pragma unroll
    for (int bi = 0; bi < 8; ++bi){
      float ig = sigmf(acc[0][bi]);
      float fg = sigmf(acc[1][bi]);
      float gg = tanhf(acc[2][bi]);
      float og = sigmf(acc[3][bi]);
      float c  = fg * c0r[bi] + ig * gg;
      c0r[bi]  = c;
      h0n[bi]  = og * tanhf(c);
    }
    __syncthreads();
    #pragma unroll
    for (int bi = 0; bi < 8; ++bi) h0[(bg * 8 + bi) * 68 + j] = h0n[bi];
    __syncthreads();

    // ---------- layer 1 ----------
    #pragma unroll
    for (int g = 0; g < 4; ++g){
      float bb = bias1[g * 64 + j];
      #pragma unroll
      for (int bi = 0; bi < 8; ++bi) acc[g][bi] = bb;
    }
    #pragma unroll 4
    for (int k4 = 0; k4 < 16; ++k4){
      float4 wv[4];
      #pragma unroll
      for (int g = 0; g < 4; ++g) wv[g] = Wih1_4[(g * 64 + j) * 16 + k4];
      #pragma unroll
      for (int bi = 0; bi < 8; ++bi){
        float4 hv = ((const float4*)h0)[(bg * 8 + bi) * 17 + k4];
        #pragma unroll
        for (int g = 0; g < 4; ++g) acc[g][bi] = dot4acc(wv[g], hv, acc[g][bi]);
      }
    }
    #pragma unroll 4
    for (int k4 = 0; k4 < 16; ++k4){
      float4 wv[4];
      #pragma unroll
      for (int g = 0; g < 4; ++g) wv[g] = Whh1_4[(g * 64 + j) * 16 + k4];
      #pragma unroll
      for (int bi = 0; bi < 8; ++bi){
        float4 hv = ((const float4*)h1)[(bg * 8 + bi) * 17 + k4];
        #pragma unroll
        for (int g = 0; g < 4; ++g) acc[g][bi] = dot4acc(wv[g], hv, acc[g][bi]);
      }
    }
    float h1n[8];
    #pragma unroll
    for (int bi = 0; bi < 8; ++bi){
      float ig = sigmf(acc[0][bi]);
      float fg = sigmf(acc[1][bi]);
      float gg = tanhf(acc[2][bi]);
      float og = sigmf(acc[3][bi]);
      float c  = fg * c1r[bi] + ig * gg;
      c1r[bi]  = c;
      h1n[bi]  = og * tanhf(c);
    }
    __syncthreads();
    #pragma unroll
    for (int bi = 0; bi < 8; ++bi) h1[(bg * 8 + bi) * 68 + j] = h1n[bi];
    __syncthreads();

    // ---------- dec1 ----------
    if (t < 192){
      const int d  = t % 96;
      const int hf = t / 96;
      float accd[16];
      float bb = b_dec1[d];
      #pragma unroll
      for (int q = 0; q < 16; ++q) accd[q] = bb;
      const float4* wr = (const float4*)(W_dec1 + (size_t)d * HDIM);
      #pragma unroll 4
      for (int k4 = 0; k4 < 16; ++k4){
        float4 w = wr[k4];
        #pragma unroll
        for (int q = 0; q < 16; ++q){
          float4 hv = ((const float4*)h1)[(hf * 16 + q) * 17 + k4];
          accd[q] = dot4acc(w, hv, accd[q]);
        }
      }
      #pragma unroll
      for (int q = 0; q < 16; ++q) d1[(hf * 16 + q) * 100 + d] = fmaxf(accd[q], 0.0f);
    }
    __syncthreads();

    // ---------- dec2 ----------
    {
      const int n  = t & 127;
      const int hf = t >> 7;
      float accd[16];
      float bb = b_dec2[n];
      #pragma unroll
      for (int q = 0; q < 16; ++q) accd[q] = bb;
      const float4* wr = (const float4*)(W_dec2 + (size_t)n * DMID);
      #pragma unroll 4
      for (int k4 = 0; k4 < 24; ++k4){
        float4 w = wr[k4];
        #pragma unroll
        for (int q = 0; q < 16; ++q){
          float4 dv = ((const float4*)d1)[(hf * 16 + q) * 25 + k4];
          accd[q] = dot4acc(w, dv, accd[q]);
        }
      }
      #pragma unroll
      for (int q = 0; q < 16; ++q) lg[(hf * 16 + q) * 128 + n] = accd[q];
    }
    __syncthreads();

    // ---------- softmax weights (f32 stores) + categorical sample ----------
    {
      const int bl  = t >> 3;
      const int s8  = t & 7;
      const int bgl = tile0 + bl;

      float lv[16];
      float lmax = -3.402823466e38f;
      #pragma unroll
      for (int i = 0; i < 16; ++i){
        lv[i] = lg[bl * 128 + s8 * 16 + i];
        lmax = fmaxf(lmax, lv[i]);
      }
      #pragma unroll
      for (int m = 1; m < 8; m <<= 1) lmax = fmaxf(lmax, __shfl_xor(lmax, m));

      float esum = 0.0f; float ev[16];
      #pragma unroll
      for (int i = 0; i < 16; ++i){
        float e = expf(lv[i] - lmax);
        ev[i] = e; esum += e;
      }
      #pragma unroll
      for (int m = 1; m < 8; m <<= 1) esum += __shfl_xor(esum, m);
      float inv = 1.0f / esum;

      // f32 weight stores, vectorized: out[b*8192 + s*128 + s8*16 .. +15]
      float4* wrow = (float4*)(out + (u64)bgl * (SEQLEN * NNEUR)
                                   + (u64)s * NNEUR + (u64)(s8 * 16));
      #pragma unroll
      for (int q = 0; q < 4; ++q)
        wrow[q] = make_float4(ev[4*q] * inv, ev[4*q+1] * inv,
                              ev[4*q+2] * inv, ev[4*q+3] * inv);

      // gumbel argmax (threefry-partitionable 32-bit bits = y0 ^ y1)
      const u32 kk0 = keyw[2 * s];
      const u32 kk1 = keyw[2 * s + 1];
      float vmax = -3.402823466e38f; int vidx = 0;
      #pragma unroll
      for (int i = 0; i < 16; ++i){
        const int n = s8 * 16 + i;
        u32 y0, y1;
        tf2x32(kk0, kk1, 0u, (u32)(bgl * 128 + n), y0, y1);
        u32 bits = y0 ^ y1;
        float f  = __uint_as_float((bits >> 9) | 0x3f800000u) - 1.0f;
        float u  = f + 1.1754943508222875e-38f;   // f*(1-tiny)+tiny folds to this in f32
        u = fmaxf(u, 1.1754943508222875e-38f);
        float gmb = -logf(-logf(u));
        float val = gmb + lv[i];
        if (val > vmax){ vmax = val; vidx = n; }
      }
      #pragma unroll
      for (int m = 1; m < 8; m <<= 1){
        float ov = __shfl_xor(vmax, m);
        int   oi = __shfl_xor(vidx, m);
        if (ov > vmax || (ov == vmax && oi < vidx)){ vmax = ov; vidx = oi; }
      }
      if (s8 == 0)
        out[(u64)NBATCH * SEQLEN * NNEUR + (u64)bgl * SEQLEN + (u64)s] = (float)vidx;
    }
    __syncthreads();
  }
}

extern "C" void kernel_launch(void* const* d_in, const int* in_sizes, int n_in,
                              void* d_out, int out_size, void* d_ws, size_t ws_size,
                              hipStream_t stream) {
  (void)in_sizes; (void)n_in; (void)out_size; (void)d_ws; (void)ws_size;
  const float* z      = (const float*)d_in[0];
  // d_in[1]=score_tensor, d_in[2]=train: unused by the reference math
  const float* W_enc1 = (const float*)d_in[3];
  const float* b_enc1 = (const float*)d_in[4];
  const float* W_enc2 = (const float*)d_in[5];
  const float* b_enc2 = (const float*)d_in[6];
  const float* W_ih0  = (const float*)d_in[7];
  const float* W_hh0  = (const float*)d_in[8];
  const float* b_ih0  = (const float*)d_in[9];
  const float* b_hh0  = (const float*)d_in[10];
  const float* W_ih1  = (const float*)d_in[11];
  const float* W_hh1  = (const float*)d_in[12];
  const float* b_ih1  = (const float*)d_in[13];
  const float* b_hh1  = (const float*)d_in[14];
  const float* W_dec1 = (const float*)d_in[15];
  const float* b_dec1 = (const float*)d_in[16];
  const float* W_dec2 = (const float*)d_in[17];
  const float* b_dec2 = (const float*)d_in[18];

  float* out = (float*)d_out;   // FLOAT32 output buffer

  dim3 grid(NBATCH / TILE);
  dim3 blk(256);
  hipLaunchKernelGGL(bar_decoder_kernel, grid, blk, 0, stream,
                     z, W_enc1, b_enc1, W_enc2, b_enc2,
                     W_ih0, W_hh0, b_ih0, b_hh0,
                     W_ih1, W_hh1, b_ih1, b_hh1,
                     W_dec1, b_dec1, W_dec2, b_dec2,
                     out);
}